// Round 16
// baseline (124.844 us; speedup 1.0000x reference)
//
#include <hip/hip_runtime.h>
#include <hip/hip_bf16.h>
#include <cmath>
#include <cstdint>

#define H_ 8
#define B_ 2
#define L_ 2048
#define D_ 512
#define SPLIT_ 4
#define LP 80   // LDS row stride (shorts): 160 B -> 2-way banks on b128 frag reads

typedef __attribute__((ext_vector_type(8))) short short8_t;
typedef __attribute__((ext_vector_type(4))) float float4_t;
typedef __attribute__((ext_vector_type(4))) unsigned short ushort4_t;
typedef __attribute__((ext_vector_type(4))) unsigned int uint4_t;

// hardware RNE f32->bf16 (compiler emits v_cvt_pk_bf16_f32 for pairs)
__device__ __forceinline__ unsigned short bf16u(float f) {
  union { __hip_bfloat16 b; unsigned short u; } c;
  c.b = __float2bfloat16(f);
  return c.u;
}
__device__ __forceinline__ unsigned bf16x2(float lo, float hi) {
  return (unsigned)bf16u(lo) | ((unsigned)bf16u(hi) << 16);
}
__device__ __forceinline__ float bf2f(unsigned short u) {
  union { unsigned u; float f; } c; c.u = (unsigned)u << 16; return c.f;
}

__device__ __forceinline__ unsigned pack8(unsigned long long x) {
  x |= x >> 4; x |= x >> 2; x |= x >> 1;
  x &= 0x0101010101010101ULL;
  return (unsigned)((x * 0x0102040810204080ULL) >> 56);
}

// ---------------------------------------------------------------- fused projection GEMMs
// z=0: Qp[hb][l][dk] (scaled 1/8)   z=1: Kp[hb][l][dk]   z=2: Vt[hb][dv][l]
__global__ __launch_bounds__(512)
void proj_gemm(const float* __restrict__ q, const float* __restrict__ k,
               const float* __restrict__ v,
               const float* __restrict__ wq, const float* __restrict__ wk,
               const float* __restrict__ wv,
               unsigned short* __restrict__ Qp, unsigned short* __restrict__ Kp,
               unsigned short* __restrict__ Vt) {
  __shared__ unsigned short As[128][LP];
  __shared__ unsigned short Bs[64][LP];
  const int tid = threadIdx.x, lane = tid & 63, wave = tid >> 6;
  const int g = lane >> 4, qi = lane & 15;
  const int m0 = blockIdx.x * 128, n0 = blockIdx.y * 64;
  const int z = blockIdx.z;
  const float* A = (z == 0) ? q : (z == 1) ? k : v;
  const float* W = (z == 0) ? wq : (z == 1) ? wk : wv;

  float4_t acc[4] = {};
  const int ar = tid >> 2, ac = (tid & 3) * 16;
  const int br = tid >> 3, bc = (tid & 7) * 8;

  for (int kt = 0; kt < 512; kt += 64) {
    const float* src = A + (size_t)(m0 + ar) * 512 + kt + ac;
    float4_t f0 = *(const float4_t*)(src);
    float4_t f1 = *(const float4_t*)(src + 4);
    float4_t f2 = *(const float4_t*)(src + 8);
    float4_t f3 = *(const float4_t*)(src + 12);
    short8_t s0, s1;
    s0[0] = bf16u(f0[0]); s0[1] = bf16u(f0[1]); s0[2] = bf16u(f0[2]); s0[3] = bf16u(f0[3]);
    s0[4] = bf16u(f1[0]); s0[5] = bf16u(f1[1]); s0[6] = bf16u(f1[2]); s0[7] = bf16u(f1[3]);
    s1[0] = bf16u(f2[0]); s1[1] = bf16u(f2[1]); s1[2] = bf16u(f2[2]); s1[3] = bf16u(f2[3]);
    s1[4] = bf16u(f3[0]); s1[5] = bf16u(f3[1]); s1[6] = bf16u(f3[2]); s1[7] = bf16u(f3[3]);
    *(short8_t*)(&As[ar][ac]) = s0;
    *(short8_t*)(&As[ar][ac + 8]) = s1;
    const float* wsrc = W + (size_t)(n0 + br) * 512 + kt + bc;
    float4_t w0 = *(const float4_t*)(wsrc);
    float4_t w1 = *(const float4_t*)(wsrc + 4);
    short8_t sw;
    sw[0] = bf16u(w0[0]); sw[1] = bf16u(w0[1]); sw[2] = bf16u(w0[2]); sw[3] = bf16u(w0[3]);
    sw[4] = bf16u(w1[0]); sw[5] = bf16u(w1[1]); sw[6] = bf16u(w1[2]); sw[7] = bf16u(w1[3]);
    *(short8_t*)(&Bs[br][bc]) = sw;
    __syncthreads();
#pragma unroll
    for (int kk = 0; kk < 2; kk++) {
      const int krow = kk * 32 + g * 8;
      short8_t a = *(const short8_t*)(&As[wave * 16 + qi][krow]);
#pragma unroll
      for (int n = 0; n < 4; n++) {
        short8_t b = *(const short8_t*)(&Bs[n * 16 + qi][krow]);
        acc[n] = __builtin_amdgcn_mfma_f32_16x16x32_bf16(a, b, acc[n], 0, 0, 0);
      }
    }
    __syncthreads();
  }

  const int gmb = m0 + wave * 16 + g * 4;
#pragma unroll
  for (int n = 0; n < 4; n++) {
    int gn = n0 + n * 16 + qi;
    int h = gn >> 6, d = gn & 63;
    if (z == 2) {
      int bb = gmb >> 11, l = gmb & 2047;
      ushort4_t o;
#pragma unroll
      for (int r = 0; r < 4; r++) o[r] = bf16u(acc[n][r]);
      *(ushort4_t*)(Vt + ((size_t)(h * B_ + bb) * 64 + d) * L_ + l) = o;
    } else {
      float sc = (z == 0) ? 0.125f : 1.0f;
      unsigned short* O = (z == 0) ? Qp : Kp;
#pragma unroll
      for (int r = 0; r < 4; r++) {
        int gm = gmb + r;
        int bb = gm >> 11, l = gm & 2047;
        O[((size_t)(h * B_ + bb) * L_ + l) * 64 + d] = bf16u(acc[n][r] * sc);
      }
    }
  }
}

// ---------------------------------------------------------------- attention (KV-split flash)
// 8 waves/block, 128 q-rows/block. Double-buffered K/V LDS, one barrier/tile.
// P relayout via shuffles (select on dest). Mask fused, 2-deep prefetch.
// s_setprio(1) around MFMA clusters (4 blocks/CU at different phases).
template<int MS>
__device__ __forceinline__ void attn_body(
    const unsigned short* __restrict__ Qp, const unsigned short* __restrict__ Kp,
    const unsigned short* __restrict__ Vt, const unsigned char* __restrict__ mask,
    unsigned short* __restrict__ Opart, float* __restrict__ MLpart,
    unsigned short (*Ks)[64][LP], unsigned short (*Vs)[64][LP]) {
  const int tid = threadIdx.x, lane = tid & 63, wave = tid >> 6;
  const int g = lane >> 4, qi = lane & 15;
  const int hb = blockIdx.y;
  const int sp = blockIdx.z;
  const int k_begin = sp * (L_ / SPLIT_), k_end = k_begin + L_ / SPLIT_;
  const int qg0 = blockIdx.x * 128 + wave * 16;
  const int qg = qg0 + qi;
  const size_t base = (size_t)hb * (L_ * 64);

  const size_t mrowoff = ((size_t)hb * L_ + qg0 + (lane >> 2)) * L_;
  const unsigned char* mb1 = mask + mrowoff + (lane & 3) * 16;              // MS==1
  const unsigned* mb4 = (const unsigned*)mask + mrowoff + (lane & 3) * 16;  // MS==4

  short8_t qf[2];
#pragma unroll
  for (int kk = 0; kk < 2; kk++)
    qf[kk] = *(const short8_t*)(Qp + base + (size_t)qg * 64 + kk * 32 + g * 8);

  float4_t o[4] = {};
  float mrun = -INFINITY, lrun = 0.f;
  const int sr = tid >> 3, sc = (tid & 7) * 8;
  const int srcA = qi * 4;
  const int srcP = qi + 32 * (g & 1);

#define LOADFB(dst, kpos)                                                        \
  do {                                                                           \
    if (MS == 1) {                                                               \
      uint4_t x = *(const uint4_t*)(mb1 + (kpos));                               \
      unsigned long long lo = ((unsigned long long)x[1] << 32) | x[0];           \
      unsigned long long hi = ((unsigned long long)x[3] << 32) | x[2];           \
      dst = pack8(lo) | (pack8(hi) << 8);                                        \
    } else {                                                                     \
      dst = 0;                                                                   \
      _Pragma("unroll")                                                          \
      for (int j = 0; j < 4; j++) {                                              \
        uint4_t x = *(const uint4_t*)(mb4 + (kpos) + j * 4);                     \
        dst |= (((unsigned)(x[0] != 0)) | ((unsigned)(x[1] != 0) << 1) |         \
                ((unsigned)(x[2] != 0) << 2) | ((unsigned)(x[3] != 0) << 3))     \
               << (j * 4);                                                       \
      }                                                                          \
    }                                                                            \
  } while (0)

  short8_t kr, vr;
  unsigned fb1, fb2;
  kr = *(const short8_t*)(Kp + base + (size_t)(k_begin + sr) * 64 + sc);
  vr = *(const short8_t*)(Vt + base + (size_t)sr * L_ + k_begin + sc);
  LOADFB(fb1, k_begin);
  fb2 = 0;
  if (k_begin + 64 < k_end) LOADFB(fb2, k_begin + 64);
  *(short8_t*)(&Ks[0][sr][sc]) = kr;
  *(short8_t*)(&Vs[0][sr][sc]) = vr;
  __syncthreads();

  int bufi = 0;
  for (int k0 = k_begin; k0 < k_end; k0 += 64) {
    const bool has_next = (k0 + 64 < k_end);
    if (has_next) {
      const int kn = k0 + 64;
      kr = *(const short8_t*)(Kp + base + (size_t)(kn + sr) * 64 + sc);
      vr = *(const short8_t*)(Vt + base + (size_t)sr * L_ + kn + sc);
    }
    unsigned fb_cur = fb1;
    fb1 = fb2;
    if (k0 + 128 < k_end) LOADFB(fb2, k0 + 128);

    unsigned nib[4];
#pragma unroll
    for (int t = 0; t < 4; t++)
      nib[t] = ((unsigned)__shfl((int)fb_cur, srcA + t, 64) >> (g * 4)) & 0xFu;

    // ---- S^T = mfma(K, Q)
    float4_t st[4] = {};
    __builtin_amdgcn_s_setprio(1);
#pragma unroll
    for (int kk = 0; kk < 2; kk++) {
      const int krow = kk * 32 + g * 8;
#pragma unroll
      for (int t = 0; t < 4; t++) {
        short8_t a = *(const short8_t*)(&Ks[bufi][t * 16 + qi][krow]);
        st[t] = __builtin_amdgcn_mfma_f32_16x16x32_bf16(a, qf[kk], st[t], 0, 0, 0);
      }
    }
    __builtin_amdgcn_s_setprio(0);

    float tmax = -INFINITY;
#pragma unroll
    for (int t = 0; t < 4; t++)
#pragma unroll
      for (int r = 0; r < 4; r++) {
        if ((nib[t] >> r) & 1u) st[t][r] = -1e10f;
        tmax = fmaxf(tmax, st[t][r]);
      }
    tmax = fmaxf(tmax, __shfl_xor(tmax, 16, 64));
    tmax = fmaxf(tmax, __shfl_xor(tmax, 32, 64));

    float nm = fmaxf(mrun, tmax);
    float fac = __expf(mrun - nm);
    mrun = nm;

    float psum = 0.f;
    unsigned w8[4][2];
#pragma unroll
    for (int t = 0; t < 4; t++) {
      float p0 = __expf(st[t][0] - nm);
      float p1 = __expf(st[t][1] - nm);
      float p2 = __expf(st[t][2] - nm);
      float p3 = __expf(st[t][3] - nm);
      psum += (p0 + p1) + (p2 + p3);
      w8[t][0] = bf16x2(p0, p1);
      w8[t][1] = bf16x2(p2, p3);
    }
    psum += __shfl_xor(psum, 16, 64);
    psum += __shfl_xor(psum, 32, 64);
    lrun = lrun * fac + psum;
#pragma unroll
    for (int n2 = 0; n2 < 4; n2++)
#pragma unroll
      for (int r = 0; r < 4; r++) o[n2][r] *= fac;

    // ---- PV: B-frag via 16 shuffles (both t-candidates, select on dest)
#pragma unroll
    for (int s = 0; s < 2; s++) {
      unsigned a00 = (unsigned)__shfl((int)w8[2 * s][0],     srcP, 64);
      unsigned a10 = (unsigned)__shfl((int)w8[2 * s + 1][0], srcP, 64);
      unsigned a01 = (unsigned)__shfl((int)w8[2 * s][1],     srcP, 64);
      unsigned a11 = (unsigned)__shfl((int)w8[2 * s + 1][1], srcP, 64);
      unsigned b00 = (unsigned)__shfl((int)w8[2 * s][0],     srcP + 16, 64);
      unsigned b10 = (unsigned)__shfl((int)w8[2 * s + 1][0], srcP + 16, 64);
      unsigned b01 = (unsigned)__shfl((int)w8[2 * s][1],     srcP + 16, 64);
      unsigned b11 = (unsigned)__shfl((int)w8[2 * s + 1][1], srcP + 16, 64);
      const bool hi = (g & 2) != 0;
      union { unsigned u[4]; short8_t s8; } pb;
      pb.u[0] = hi ? a10 : a00;
      pb.u[1] = hi ? a11 : a01;
      pb.u[2] = hi ? b10 : b00;
      pb.u[3] = hi ? b11 : b01;
      __builtin_amdgcn_s_setprio(1);
#pragma unroll
      for (int n2 = 0; n2 < 4; n2++) {
        short8_t a = *(const short8_t*)(&Vs[bufi][n2 * 16 + qi][s * 32 + g * 8]);
        o[n2] = __builtin_amdgcn_mfma_f32_16x16x32_bf16(a, pb.s8, o[n2], 0, 0, 0);
      }
      __builtin_amdgcn_s_setprio(0);
    }

    if (has_next) {
      *(short8_t*)(&Ks[bufi ^ 1][sr][sc]) = kr;
      *(short8_t*)(&Vs[bufi ^ 1][sr][sc]) = vr;
      __syncthreads();
      bufi ^= 1;
    }
  }
#undef LOADFB

  const size_t pb = (((size_t)sp * 16 + hb) * L_ + qg) * 64;
#pragma unroll
  for (int n2 = 0; n2 < 4; n2++) {
    ushort4_t ov;
#pragma unroll
    for (int r = 0; r < 4; r++) ov[r] = bf16u(o[n2][r]);
    *(ushort4_t*)(Opart + pb + n2 * 16 + g * 4) = ov;
  }
  if (lane < 16) {
    float* ml = MLpart + (((size_t)sp * 16 + hb) * L_ + qg) * 2;
    ml[0] = mrun; ml[1] = lrun;
  }
}

__global__ __launch_bounds__(512)
void attn_split(const unsigned short* __restrict__ Qp, const unsigned short* __restrict__ Kp,
                const unsigned short* __restrict__ Vt, const unsigned char* __restrict__ mask,
                unsigned short* __restrict__ Opart, float* __restrict__ MLpart) {
  __shared__ unsigned short Ks[2][64][LP];
  __shared__ unsigned short Vs[2][64][LP];
  // dtype self-detection: int32 {0,1} words never exceed 1; random bool bytes do.
  unsigned probe = ((const unsigned*)mask)[threadIdx.x & 63];
  if (__any(probe > 1u))
    attn_body<1>(Qp, Kp, Vt, mask, Opart, MLpart, Ks, Vs);
  else
    attn_body<4>(Qp, Kp, Vt, mask, Opart, MLpart, Ks, Vs);
}

// ---------------------------------------------------------------- FC GEMM + split-combine + bias + residual
// A-staging performs the flash-split merge: A[m][h*64+dv] =
//   sum_s Opart[s][hb][l][dv] * e_s / sum_s l_s e_s   (hb = 2h + (m>>11), l = m&2047)
__global__ __launch_bounds__(512)
void fc_gemm(const unsigned short* __restrict__ Opart, const float* __restrict__ MLpart,
             const float* __restrict__ wfc, const float* __restrict__ resid,
             const float* __restrict__ bfc, float* __restrict__ out) {
  __shared__ unsigned short As[128][LP];
  __shared__ unsigned short Bs[64][LP];
  const int tid = threadIdx.x, lane = tid & 63, wave = tid >> 6;
  const int g = lane >> 4, qi = lane & 15;
  const int m0 = blockIdx.x * 128, n0 = blockIdx.y * 64;
  float4_t acc[4] = {};
  const int ar = tid >> 2, ac = (tid & 3) * 16;
  const int br = tid >> 3, bc = (tid & 7) * 8;
  const int m = m0 + ar;
  const int bb = m >> 11, l = m & 2047;

  for (int kt = 0; kt < 512; kt += 64) {
    // ---- combine-on-stage: 16 output cols (h fixed within the chunk)
    const int h = kt >> 6;
    const int hb = h * 2 + bb;
    float ms[SPLIT_], ls[SPLIT_];
    float M = -INFINITY;
#pragma unroll
    for (int s = 0; s < SPLIT_; s++) {
      const float* ml = MLpart + (((size_t)s * 16 + hb) * L_ + l) * 2;
      ms[s] = ml[0]; ls[s] = ml[1];
      M = fmaxf(M, ms[s]);
    }
    float den = 0.f, e[SPLIT_];
#pragma unroll
    for (int s = 0; s < SPLIT_; s++) { e[s] = __expf(ms[s] - M); den += ls[s] * e[s]; }
    float inv = 1.0f / den;
    float a16[16] = {};
#pragma unroll
    for (int s = 0; s < SPLIT_; s++) {
      const unsigned short* p = Opart + ((((size_t)s * 16 + hb) * L_ + l) * 64 + ac);
      ushort4_t p0 = *(const ushort4_t*)(p);
      ushort4_t p1 = *(const ushort4_t*)(p + 4);
      ushort4_t p2 = *(const ushort4_t*)(p + 8);
      ushort4_t p3 = *(const ushort4_t*)(p + 12);
      float w = e[s] * inv;
#pragma unroll
      for (int j = 0; j < 4; j++) {
        a16[j]      += bf2f(p0[j]) * w;
        a16[4 + j]  += bf2f(p1[j]) * w;
        a16[8 + j]  += bf2f(p2[j]) * w;
        a16[12 + j] += bf2f(p3[j]) * w;
      }
    }
    short8_t s0, s1;
#pragma unroll
    for (int j = 0; j < 8; j++) { s0[j] = bf16u(a16[j]); s1[j] = bf16u(a16[8 + j]); }
    *(short8_t*)(&As[ar][ac]) = s0;
    *(short8_t*)(&As[ar][ac + 8]) = s1;

    const float* wsrc = wfc + (size_t)(n0 + br) * 512 + kt + bc;
    float4_t w0 = *(const float4_t*)(wsrc);
    float4_t w1 = *(const float4_t*)(wsrc + 4);
    short8_t sw;
    sw[0] = bf16u(w0[0]); sw[1] = bf16u(w0[1]); sw[2] = bf16u(w0[2]); sw[3] = bf16u(w0[3]);
    sw[4] = bf16u(w1[0]); sw[5] = bf16u(w1[1]); sw[6] = bf16u(w1[2]); sw[7] = bf16u(w1[3]);
    *(short8_t*)(&Bs[br][bc]) = sw;
    __syncthreads();
#pragma unroll
    for (int kk = 0; kk < 2; kk++) {
      const int krow = kk * 32 + g * 8;
      short8_t a = *(const short8_t*)(&As[wave * 16 + qi][krow]);
#pragma unroll
      for (int n = 0; n < 4; n++) {
        short8_t b = *(const short8_t*)(&Bs[n * 16 + qi][krow]);
        acc[n] = __builtin_amdgcn_mfma_f32_16x16x32_bf16(a, b, acc[n], 0, 0, 0);
      }
    }
    __syncthreads();
  }

  const int gmb = m0 + wave * 16 + g * 4;
#pragma unroll
  for (int n = 0; n < 4; n++) {
    int gn = n0 + n * 16 + qi;
    float bv = bfc[gn];
#pragma unroll
    for (int r = 0; r < 4; r++) {
      int gm = gmb + r;
      out[(size_t)gm * 512 + gn] = acc[n][r] + bv + resid[(size_t)gm * 512 + gn];
    }
  }
}

// ---------------------------------------------------------------- LayerNorm (in place), 1 wave / row
__global__ __launch_bounds__(256)
void ln_kernel(float* __restrict__ Z, const float* __restrict__ gamma,
               const float* __restrict__ beta) {
  const int row = blockIdx.x * 4 + (threadIdx.x >> 6);
  const int lane = threadIdx.x & 63;
  float* zp = Z + (size_t)row * 512 + lane * 8;
  float4_t x0 = *(const float4_t*)(zp);
  float4_t x1 = *(const float4_t*)(zp + 4);
  float s = 0.f, s2 = 0.f;
#pragma unroll
  for (int j = 0; j < 4; j++) { s += x0[j] + x1[j]; s2 += x0[j] * x0[j] + x1[j] * x1[j]; }
#pragma unroll
  for (int mm = 1; mm < 64; mm <<= 1) { s += __shfl_xor(s, mm, 64); s2 += __shfl_xor(s2, mm, 64); }
  float mu = s * (1.f / 512.f);
  float var = s2 * (1.f / 512.f) - mu * mu;
  float inv = rsqrtf(var + 1e-5f);
  float4_t g0 = *(const float4_t*)(gamma + lane * 8);
  float4_t g1 = *(const float4_t*)(gamma + lane * 8 + 4);
  float4_t b0 = *(const float4_t*)(beta + lane * 8);
  float4_t b1 = *(const float4_t*)(beta + lane * 8 + 4);
#pragma unroll
  for (int j = 0; j < 4; j++) {
    x0[j] = g0[j] * (x0[j] - mu) * inv + b0[j];
    x1[j] = g1[j] * (x1[j] - mu) * inv + b1[j];
  }
  *(float4_t*)(zp) = x0;
  *(float4_t*)(zp + 4) = x1;
}

// ---------------------------------------------------------------- launch
extern "C" void kernel_launch(void* const* d_in, const int* in_sizes, int n_in,
                              void* d_out, int out_size, void* d_ws, size_t ws_size,
                              hipStream_t stream) {
  const float* q   = (const float*)d_in[0];
  const float* k   = (const float*)d_in[1];
  const float* v   = (const float*)d_in[2];
  const unsigned char* mask = (const unsigned char*)d_in[3];
  const float* Wq  = (const float*)d_in[4];
  const float* Wk  = (const float*)d_in[5];
  const float* Wv  = (const float*)d_in[6];
  const float* Wfc = (const float*)d_in[7];
  const float* bfc = (const float*)d_in[8];
  const float* gamma = (const float*)d_in[9];
  const float* beta  = (const float*)d_in[10];
  float* out = (float*)d_out;

  char* ws = (char*)d_ws;
  unsigned short* Qp   = (unsigned short*)(ws);
  unsigned short* Kp   = Qp + 2097152;
  unsigned short* Vt   = Kp + 2097152;
  unsigned short* Opart = Vt + 2097152;                           // 16.8 MB (bf16, SPLIT=4)
  float* MLpart = (float*)(Opart + (size_t)SPLIT_ * 16 * L_ * 64); // 1.05 MB

  proj_gemm<<<dim3(32, 8, 3), 512, 0, stream>>>(q, k, v, Wq, Wk, Wv, Qp, Kp, Vt);
  attn_split<<<dim3(16, 16, SPLIT_), 512, 0, stream>>>(Qp, Kp, Vt, mask, Opart, MLpart);
  fc_gemm<<<dim3(32, 8), 512, 0, stream>>>(Opart, MLpart, Wfc, q, bfc, out);
  ln_kernel<<<1024, 256, 0, stream>>>(out, gamma, beta);
}

// Round 17
// 118.983 us; speedup vs baseline: 1.0493x; 1.0493x over previous
//
#include <hip/hip_runtime.h>
#include <hip/hip_bf16.h>
#include <cmath>
#include <cstdint>

#define H_ 8
#define B_ 2
#define L_ 2048
#define D_ 512
#define SPLIT_ 4
#define LP 80   // LDS row stride (shorts): 160 B -> 2-way banks on b128 frag reads

typedef __attribute__((ext_vector_type(8))) short short8_t;
typedef __attribute__((ext_vector_type(4))) float float4_t;
typedef __attribute__((ext_vector_type(4))) unsigned short ushort4_t;
typedef __attribute__((ext_vector_type(4))) unsigned int uint4_t;

// hardware RNE f32->bf16 (compiler emits v_cvt_pk_bf16_f32 for pairs)
__device__ __forceinline__ unsigned short bf16u(float f) {
  union { __hip_bfloat16 b; unsigned short u; } c;
  c.b = __float2bfloat16(f);
  return c.u;
}
__device__ __forceinline__ unsigned bf16x2(float lo, float hi) {
  return (unsigned)bf16u(lo) | ((unsigned)bf16u(hi) << 16);
}
__device__ __forceinline__ float bf2f(unsigned short u) {
  union { unsigned u; float f; } c; c.u = (unsigned)u << 16; return c.f;
}

__device__ __forceinline__ unsigned pack8(unsigned long long x) {
  x |= x >> 4; x |= x >> 2; x |= x >> 1;
  x &= 0x0101010101010101ULL;
  return (unsigned)((x * 0x0102040810204080ULL) >> 56);
}

// ---------------------------------------------------------------- fused projection GEMMs
// z=0: Qp[hb][l][dk] (scaled 1/8)   z=1: Kp[hb][l][dk]   z=2: Vt[hb][dv][l]
__global__ __launch_bounds__(512)
void proj_gemm(const float* __restrict__ q, const float* __restrict__ k,
               const float* __restrict__ v,
               const float* __restrict__ wq, const float* __restrict__ wk,
               const float* __restrict__ wv,
               unsigned short* __restrict__ Qp, unsigned short* __restrict__ Kp,
               unsigned short* __restrict__ Vt) {
  __shared__ unsigned short As[128][LP];
  __shared__ unsigned short Bs[64][LP];
  const int tid = threadIdx.x, lane = tid & 63, wave = tid >> 6;
  const int g = lane >> 4, qi = lane & 15;
  const int m0 = blockIdx.x * 128, n0 = blockIdx.y * 64;
  const int z = blockIdx.z;
  const float* A = (z == 0) ? q : (z == 1) ? k : v;
  const float* W = (z == 0) ? wq : (z == 1) ? wk : wv;

  float4_t acc[4] = {};
  const int ar = tid >> 2, ac = (tid & 3) * 16;
  const int br = tid >> 3, bc = (tid & 7) * 8;

  for (int kt = 0; kt < 512; kt += 64) {
    const float* src = A + (size_t)(m0 + ar) * 512 + kt + ac;
    float4_t f0 = *(const float4_t*)(src);
    float4_t f1 = *(const float4_t*)(src + 4);
    float4_t f2 = *(const float4_t*)(src + 8);
    float4_t f3 = *(const float4_t*)(src + 12);
    short8_t s0, s1;
    s0[0] = bf16u(f0[0]); s0[1] = bf16u(f0[1]); s0[2] = bf16u(f0[2]); s0[3] = bf16u(f0[3]);
    s0[4] = bf16u(f1[0]); s0[5] = bf16u(f1[1]); s0[6] = bf16u(f1[2]); s0[7] = bf16u(f1[3]);
    s1[0] = bf16u(f2[0]); s1[1] = bf16u(f2[1]); s1[2] = bf16u(f2[2]); s1[3] = bf16u(f2[3]);
    s1[4] = bf16u(f3[0]); s1[5] = bf16u(f3[1]); s1[6] = bf16u(f3[2]); s1[7] = bf16u(f3[3]);
    *(short8_t*)(&As[ar][ac]) = s0;
    *(short8_t*)(&As[ar][ac + 8]) = s1;
    const float* wsrc = W + (size_t)(n0 + br) * 512 + kt + bc;
    float4_t w0 = *(const float4_t*)(wsrc);
    float4_t w1 = *(const float4_t*)(wsrc + 4);
    short8_t sw;
    sw[0] = bf16u(w0[0]); sw[1] = bf16u(w0[1]); sw[2] = bf16u(w0[2]); sw[3] = bf16u(w0[3]);
    sw[4] = bf16u(w1[0]); sw[5] = bf16u(w1[1]); sw[6] = bf16u(w1[2]); sw[7] = bf16u(w1[3]);
    *(short8_t*)(&Bs[br][bc]) = sw;
    __syncthreads();
#pragma unroll
    for (int kk = 0; kk < 2; kk++) {
      const int krow = kk * 32 + g * 8;
      short8_t a = *(const short8_t*)(&As[wave * 16 + qi][krow]);
#pragma unroll
      for (int n = 0; n < 4; n++) {
        short8_t b = *(const short8_t*)(&Bs[n * 16 + qi][krow]);
        acc[n] = __builtin_amdgcn_mfma_f32_16x16x32_bf16(a, b, acc[n], 0, 0, 0);
      }
    }
    __syncthreads();
  }

  const int gmb = m0 + wave * 16 + g * 4;
#pragma unroll
  for (int n = 0; n < 4; n++) {
    int gn = n0 + n * 16 + qi;
    int h = gn >> 6, d = gn & 63;
    if (z == 2) {
      int bb = gmb >> 11, l = gmb & 2047;
      ushort4_t o;
#pragma unroll
      for (int r = 0; r < 4; r++) o[r] = bf16u(acc[n][r]);
      *(ushort4_t*)(Vt + ((size_t)(h * B_ + bb) * 64 + d) * L_ + l) = o;
    } else {
      float sc = (z == 0) ? 0.125f : 1.0f;
      unsigned short* O = (z == 0) ? Qp : Kp;
#pragma unroll
      for (int r = 0; r < 4; r++) {
        int gm = gmb + r;
        int bb = gm >> 11, l = gm & 2047;
        O[((size_t)(h * B_ + bb) * L_ + l) * 64 + d] = bf16u(acc[n][r] * sc);
      }
    }
  }
}

// ---------------------------------------------------------------- attention (KV-split flash)
// 8 waves/block, 128 q-rows/block. Double-buffered K/V LDS, one barrier/tile.
// P relayout via shuffles (select on dest). Mask fused, 2-deep prefetch.
// XCD-swizzled block ids: each XCD owns 2 head-batches -> K/V L2-resident.
template<int MS>
__device__ __forceinline__ void attn_body(
    const unsigned short* __restrict__ Qp, const unsigned short* __restrict__ Kp,
    const unsigned short* __restrict__ Vt, const unsigned char* __restrict__ mask,
    unsigned short* __restrict__ Opart, float* __restrict__ MLpart,
    unsigned short (*Ks)[64][LP], unsigned short (*Vs)[64][LP],
    int bx, int hb, int sp) {
  const int tid = threadIdx.x, lane = tid & 63, wave = tid >> 6;
  const int g = lane >> 4, qi = lane & 15;
  const int k_begin = sp * (L_ / SPLIT_), k_end = k_begin + L_ / SPLIT_;
  const int qg0 = bx * 128 + wave * 16;
  const int qg = qg0 + qi;
  const size_t base = (size_t)hb * (L_ * 64);

  const size_t mrowoff = ((size_t)hb * L_ + qg0 + (lane >> 2)) * L_;
  const unsigned char* mb1 = mask + mrowoff + (lane & 3) * 16;              // MS==1
  const unsigned* mb4 = (const unsigned*)mask + mrowoff + (lane & 3) * 16;  // MS==4

  short8_t qf[2];
#pragma unroll
  for (int kk = 0; kk < 2; kk++)
    qf[kk] = *(const short8_t*)(Qp + base + (size_t)qg * 64 + kk * 32 + g * 8);

  float4_t o[4] = {};
  float mrun = -INFINITY, lrun = 0.f;
  const int sr = tid >> 3, sc = (tid & 7) * 8;
  const int srcA = qi * 4;
  const int srcP = qi + 32 * (g & 1);

#define LOADFB(dst, kpos)                                                        \
  do {                                                                           \
    if (MS == 1) {                                                               \
      uint4_t x = *(const uint4_t*)(mb1 + (kpos));                               \
      unsigned long long lo = ((unsigned long long)x[1] << 32) | x[0];           \
      unsigned long long hi = ((unsigned long long)x[3] << 32) | x[2];           \
      dst = pack8(lo) | (pack8(hi) << 8);                                        \
    } else {                                                                     \
      dst = 0;                                                                   \
      _Pragma("unroll")                                                          \
      for (int j = 0; j < 4; j++) {                                              \
        uint4_t x = *(const uint4_t*)(mb4 + (kpos) + j * 4);                     \
        dst |= (((unsigned)(x[0] != 0)) | ((unsigned)(x[1] != 0) << 1) |         \
                ((unsigned)(x[2] != 0) << 2) | ((unsigned)(x[3] != 0) << 3))     \
               << (j * 4);                                                       \
      }                                                                          \
    }                                                                            \
  } while (0)

  short8_t kr, vr;
  unsigned fb1, fb2;
  kr = *(const short8_t*)(Kp + base + (size_t)(k_begin + sr) * 64 + sc);
  vr = *(const short8_t*)(Vt + base + (size_t)sr * L_ + k_begin + sc);
  LOADFB(fb1, k_begin);
  fb2 = 0;
  if (k_begin + 64 < k_end) LOADFB(fb2, k_begin + 64);
  *(short8_t*)(&Ks[0][sr][sc]) = kr;
  *(short8_t*)(&Vs[0][sr][sc]) = vr;
  __syncthreads();

  int bufi = 0;
  for (int k0 = k_begin; k0 < k_end; k0 += 64) {
    const bool has_next = (k0 + 64 < k_end);
    if (has_next) {
      const int kn = k0 + 64;
      kr = *(const short8_t*)(Kp + base + (size_t)(kn + sr) * 64 + sc);
      vr = *(const short8_t*)(Vt + base + (size_t)sr * L_ + kn + sc);
    }
    unsigned fb_cur = fb1;
    fb1 = fb2;
    if (k0 + 128 < k_end) LOADFB(fb2, k0 + 128);

    unsigned nib[4];
#pragma unroll
    for (int t = 0; t < 4; t++)
      nib[t] = ((unsigned)__shfl((int)fb_cur, srcA + t, 64) >> (g * 4)) & 0xFu;

    // ---- S^T = mfma(K, Q)
    float4_t st[4] = {};
#pragma unroll
    for (int kk = 0; kk < 2; kk++) {
      const int krow = kk * 32 + g * 8;
#pragma unroll
      for (int t = 0; t < 4; t++) {
        short8_t a = *(const short8_t*)(&Ks[bufi][t * 16 + qi][krow]);
        st[t] = __builtin_amdgcn_mfma_f32_16x16x32_bf16(a, qf[kk], st[t], 0, 0, 0);
      }
    }

    float tmax = -INFINITY;
#pragma unroll
    for (int t = 0; t < 4; t++)
#pragma unroll
      for (int r = 0; r < 4; r++) {
        if ((nib[t] >> r) & 1u) st[t][r] = -1e10f;
        tmax = fmaxf(tmax, st[t][r]);
      }
    tmax = fmaxf(tmax, __shfl_xor(tmax, 16, 64));
    tmax = fmaxf(tmax, __shfl_xor(tmax, 32, 64));

    float nm = fmaxf(mrun, tmax);
    float fac = __expf(mrun - nm);
    mrun = nm;

    float psum = 0.f;
    unsigned w8[4][2];
#pragma unroll
    for (int t = 0; t < 4; t++) {
      float p0 = __expf(st[t][0] - nm);
      float p1 = __expf(st[t][1] - nm);
      float p2 = __expf(st[t][2] - nm);
      float p3 = __expf(st[t][3] - nm);
      psum += (p0 + p1) + (p2 + p3);
      w8[t][0] = bf16x2(p0, p1);
      w8[t][1] = bf16x2(p2, p3);
    }
    psum += __shfl_xor(psum, 16, 64);
    psum += __shfl_xor(psum, 32, 64);
    lrun = lrun * fac + psum;
#pragma unroll
    for (int n2 = 0; n2 < 4; n2++)
#pragma unroll
      for (int r = 0; r < 4; r++) o[n2][r] *= fac;

    // ---- PV: B-frag via 16 shuffles (both t-candidates, select on dest)
#pragma unroll
    for (int s = 0; s < 2; s++) {
      unsigned a00 = (unsigned)__shfl((int)w8[2 * s][0],     srcP, 64);
      unsigned a10 = (unsigned)__shfl((int)w8[2 * s + 1][0], srcP, 64);
      unsigned a01 = (unsigned)__shfl((int)w8[2 * s][1],     srcP, 64);
      unsigned a11 = (unsigned)__shfl((int)w8[2 * s + 1][1], srcP, 64);
      unsigned b00 = (unsigned)__shfl((int)w8[2 * s][0],     srcP + 16, 64);
      unsigned b10 = (unsigned)__shfl((int)w8[2 * s + 1][0], srcP + 16, 64);
      unsigned b01 = (unsigned)__shfl((int)w8[2 * s][1],     srcP + 16, 64);
      unsigned b11 = (unsigned)__shfl((int)w8[2 * s + 1][1], srcP + 16, 64);
      const bool hi = (g & 2) != 0;
      union { unsigned u[4]; short8_t s8; } pb;
      pb.u[0] = hi ? a10 : a00;
      pb.u[1] = hi ? a11 : a01;
      pb.u[2] = hi ? b10 : b00;
      pb.u[3] = hi ? b11 : b01;
#pragma unroll
      for (int n2 = 0; n2 < 4; n2++) {
        short8_t a = *(const short8_t*)(&Vs[bufi][n2 * 16 + qi][s * 32 + g * 8]);
        o[n2] = __builtin_amdgcn_mfma_f32_16x16x32_bf16(a, pb.s8, o[n2], 0, 0, 0);
      }
    }

    if (has_next) {
      *(short8_t*)(&Ks[bufi ^ 1][sr][sc]) = kr;
      *(short8_t*)(&Vs[bufi ^ 1][sr][sc]) = vr;
      __syncthreads();
      bufi ^= 1;
    }
  }
#undef LOADFB

  const size_t pb = (((size_t)sp * 16 + hb) * L_ + qg) * 64;
#pragma unroll
  for (int n2 = 0; n2 < 4; n2++) {
    ushort4_t ov;
#pragma unroll
    for (int r = 0; r < 4; r++) ov[r] = bf16u(o[n2][r]);
    *(ushort4_t*)(Opart + pb + n2 * 16 + g * 4) = ov;
  }
  if (lane < 16) {
    float* ml = MLpart + (((size_t)sp * 16 + hb) * L_ + qg) * 2;
    ml[0] = mrun; ml[1] = lrun;
  }
}

__global__ __launch_bounds__(512)
void attn_split(const unsigned short* __restrict__ Qp, const unsigned short* __restrict__ Kp,
                const unsigned short* __restrict__ Vt, const unsigned char* __restrict__ mask,
                unsigned short* __restrict__ Opart, float* __restrict__ MLpart) {
  __shared__ unsigned short Ks[2][64][LP];
  __shared__ unsigned short Vs[2][64][LP];
  // Bijective XCD swizzle: 1024 blocks = 8 XCDs x 128. XCD c gets swz range
  // [c*128,(c+1)*128) -> hb in {2c, 2c+1}: K/V working set 1 MB per XCD L2.
  const int id = blockIdx.x + 16 * (blockIdx.y + 16 * blockIdx.z);
  const int swz = (id & 7) * 128 + (id >> 3);
  const int hb = swz >> 6;
  const int sp = (swz >> 4) & 3;
  const int bx = swz & 15;
  // dtype self-detection: int32 {0,1} words never exceed 1; random bool bytes do.
  unsigned probe = ((const unsigned*)mask)[threadIdx.x & 63];
  if (__any(probe > 1u))
    attn_body<1>(Qp, Kp, Vt, mask, Opart, MLpart, Ks, Vs, bx, hb, sp);
  else
    attn_body<4>(Qp, Kp, Vt, mask, Opart, MLpart, Ks, Vs, bx, hb, sp);
}

// ---------------------------------------------------------------- combine splits -> Y bf16
__global__ __launch_bounds__(256)
void attn_combine(const unsigned short* __restrict__ Opart, const float* __restrict__ MLpart,
                  unsigned short* __restrict__ Y) {
  int gid = blockIdx.x * 256 + threadIdx.x;   // 16*2048*8 threads
  int dvc = (gid & 7) * 8;
  int hbq = gid >> 3;
  int hb = hbq >> 11, qq = hbq & 2047;
  int h = hb >> 1, bb = hb & 1;
  float m[SPLIT_], l[SPLIT_];
  float M = -INFINITY;
#pragma unroll
  for (int s = 0; s < SPLIT_; s++) {
    const float* ml = MLpart + (((size_t)s * 16 + hb) * L_ + qq) * 2;
    m[s] = ml[0]; l[s] = ml[1];
    M = fmaxf(M, m[s]);
  }
  float denom = 0.f, e[SPLIT_];
#pragma unroll
  for (int s = 0; s < SPLIT_; s++) { e[s] = __expf(m[s] - M); denom += l[s] * e[s]; }
  float inv = 1.0f / denom;
  float acc[8] = {};
#pragma unroll
  for (int s = 0; s < SPLIT_; s++) {
    const unsigned short* p = Opart + (((size_t)s * 16 + hb) * L_ + qq) * 64 + dvc;
    ushort4_t a0 = *(const ushort4_t*)(p);
    ushort4_t a1 = *(const ushort4_t*)(p + 4);
    float w = e[s] * inv;
#pragma unroll
    for (int j = 0; j < 4; j++) {
      acc[j] += bf2f(a0[j]) * w;
      acc[j + 4] += bf2f(a1[j]) * w;
    }
  }
  short8_t ov;
#pragma unroll
  for (int j = 0; j < 8; j++) ov[j] = bf16u(acc[j]);
  *(short8_t*)(Y + ((size_t)(bb * L_ + qq)) * 512 + h * 64 + dvc) = ov;
}

// ---------------------------------------------------------------- FC GEMM + bias + residual
// (W converted f32->bf16 inline during B-staging)
__global__ __launch_bounds__(512)
void fc_gemm(const unsigned short* __restrict__ Yb, const float* __restrict__ wfc,
             const float* __restrict__ resid, const float* __restrict__ bfc,
             float* __restrict__ out) {
  __shared__ unsigned short As[128][LP];
  __shared__ unsigned short Bs[64][LP];
  const int tid = threadIdx.x, lane = tid & 63, wave = tid >> 6;
  const int g = lane >> 4, qi = lane & 15;
  const int m0 = blockIdx.x * 128, n0 = blockIdx.y * 64;
  float4_t acc[4] = {};
  const int ar = tid >> 2, ac = (tid & 3) * 16;
  const int br = tid >> 3, bc = (tid & 7) * 8;

  for (int kt = 0; kt < 512; kt += 64) {
    const unsigned short* src = Yb + (size_t)(m0 + ar) * 512 + kt + ac;
    *(short8_t*)(&As[ar][ac]) = *(const short8_t*)(src);
    *(short8_t*)(&As[ar][ac + 8]) = *(const short8_t*)(src + 8);
    const float* wsrc = wfc + (size_t)(n0 + br) * 512 + kt + bc;
    float4_t w0 = *(const float4_t*)(wsrc);
    float4_t w1 = *(const float4_t*)(wsrc + 4);
    short8_t sw;
    sw[0] = bf16u(w0[0]); sw[1] = bf16u(w0[1]); sw[2] = bf16u(w0[2]); sw[3] = bf16u(w0[3]);
    sw[4] = bf16u(w1[0]); sw[5] = bf16u(w1[1]); sw[6] = bf16u(w1[2]); sw[7] = bf16u(w1[3]);
    *(short8_t*)(&Bs[br][bc]) = sw;
    __syncthreads();
#pragma unroll
    for (int kk = 0; kk < 2; kk++) {
      const int krow = kk * 32 + g * 8;
      short8_t a = *(const short8_t*)(&As[wave * 16 + qi][krow]);
#pragma unroll
      for (int n = 0; n < 4; n++) {
        short8_t b = *(const short8_t*)(&Bs[n * 16 + qi][krow]);
        acc[n] = __builtin_amdgcn_mfma_f32_16x16x32_bf16(a, b, acc[n], 0, 0, 0);
      }
    }
    __syncthreads();
  }

  const int gmb = m0 + wave * 16 + g * 4;
#pragma unroll
  for (int n = 0; n < 4; n++) {
    int gn = n0 + n * 16 + qi;
    float bv = bfc[gn];
#pragma unroll
    for (int r = 0; r < 4; r++) {
      int gm = gmb + r;
      out[(size_t)gm * 512 + gn] = acc[n][r] + bv + resid[(size_t)gm * 512 + gn];
    }
  }
}

// ---------------------------------------------------------------- LayerNorm (in place), 1 wave / row
__global__ __launch_bounds__(256)
void ln_kernel(float* __restrict__ Z, const float* __restrict__ gamma,
               const float* __restrict__ beta) {
  const int row = blockIdx.x * 4 + (threadIdx.x >> 6);
  const int lane = threadIdx.x & 63;
  float* zp = Z + (size_t)row * 512 + lane * 8;
  float4_t x0 = *(const float4_t*)(zp);
  float4_t x1 = *(const float4_t*)(zp + 4);
  float s = 0.f, s2 = 0.f;
#pragma unroll
  for (int j = 0; j < 4; j++) { s += x0[j] + x1[j]; s2 += x0[j] * x0[j] + x1[j] * x1[j]; }
#pragma unroll
  for (int mm = 1; mm < 64; mm <<= 1) { s += __shfl_xor(s, mm, 64); s2 += __shfl_xor(s2, mm, 64); }
  float mu = s * (1.f / 512.f);
  float var = s2 * (1.f / 512.f) - mu * mu;
  float inv = rsqrtf(var + 1e-5f);
  float4_t g0 = *(const float4_t*)(gamma + lane * 8);
  float4_t g1 = *(const float4_t*)(gamma + lane * 8 + 4);
  float4_t b0 = *(const float4_t*)(beta + lane * 8);
  float4_t b1 = *(const float4_t*)(beta + lane * 8 + 4);
#pragma unroll
  for (int j = 0; j < 4; j++) {
    x0[j] = g0[j] * (x0[j] - mu) * inv + b0[j];
    x1[j] = g1[j] * (x1[j] - mu) * inv + b1[j];
  }
  *(float4_t*)(zp) = x0;
  *(float4_t*)(zp + 4) = x1;
}

// ---------------------------------------------------------------- launch
extern "C" void kernel_launch(void* const* d_in, const int* in_sizes, int n_in,
                              void* d_out, int out_size, void* d_ws, size_t ws_size,
                              hipStream_t stream) {
  const float* q   = (const float*)d_in[0];
  const float* k   = (const float*)d_in[1];
  const float* v   = (const float*)d_in[2];
  const unsigned char* mask = (const unsigned char*)d_in[3];
  const float* Wq  = (const float*)d_in[4];
  const float* Wk  = (const float*)d_in[5];
  const float* Wv  = (const float*)d_in[6];
  const float* Wfc = (const float*)d_in[7];
  const float* bfc = (const float*)d_in[8];
  const float* gamma = (const float*)d_in[9];
  const float* beta  = (const float*)d_in[10];
  float* out = (float*)d_out;

  char* ws = (char*)d_ws;
  unsigned short* Qp   = (unsigned short*)(ws);
  unsigned short* Kp   = Qp + 2097152;
  unsigned short* Vt   = Kp + 2097152;
  unsigned short* Y    = Vt + 2097152;
  unsigned short* Opart = Y + 2097152;                            // 16.8 MB (bf16, SPLIT=4)
  float* MLpart = (float*)(Opart + (size_t)SPLIT_ * 16 * L_ * 64); // 1.05 MB

  proj_gemm<<<dim3(32, 8, 3), 512, 0, stream>>>(q, k, v, Wq, Wk, Wv, Qp, Kp, Vt);
  attn_split<<<dim3(16, 16, SPLIT_), 512, 0, stream>>>(Qp, Kp, Vt, mask, Opart, MLpart);
  attn_combine<<<1024, 256, 0, stream>>>(Opart, MLpart, Y);
  fc_gemm<<<dim3(32, 8), 512, 0, stream>>>(Y, Wfc, q, bfc, out);
  ln_kernel<<<1024, 256, 0, stream>>>(out, gamma, beta);
}